// Round 1
// baseline (130.580 us; speedup 1.0000x reference)
//
#include <hip/hip_runtime.h>
#include <math.h>

#define B_N 2048
#define DIM 32
#define K_N 10
#define NP  528   // number of sorted pairs (i<=j), D=32

// ---- ws layout (4-byte words) ----
#define WS_CW      0              // cw[K] int
#define WS_CURSOR  16             // cursor[K] int
#define WS_OFFS    32             // offs[K] int
#define WS_LOSS    48             // lossAcc float
#define WS_KB      64             // kb[B] int
#define WS_DIFFC   (64 + B_N)     // diffc[B*32] float

// compress(m, c_add, p, c_sub) = sign(sign(m)+0.1) * (pow(|m|+c_add, p) - c_sub)
__device__ __forceinline__ float c2f(float x) {
  float r = sqrtf(fabsf(x) + 0.25f) - 0.5f;
  return (x >= 0.f) ? r : -r;
}
__device__ __forceinline__ float c3f(float x) {
  float r = cbrtf(fabsf(x) + 0.19245008973f) - 0.57735026919f;
  return (x >= 0.f) ? r : -r;
}
__device__ __forceinline__ float c4f(float x) {
  float r = sqrtf(sqrtf(fabsf(x) + 0.15749013123f)) - 0.62996052494f;
  return (x >= 0.f) ? r : -r;
}
#define T4C1 (sqrtf(sqrtf(1.f + 0.15749013123f)) - 0.62996052494f)  // compress(1) for order 4

__device__ __forceinline__ void block_atomic_reduce(float v, float* target, float scale) {
  __shared__ float sred[16];
  #pragma unroll
  for (int off = 32; off > 0; off >>= 1) v += __shfl_down(v, off, 64);
  int lane = threadIdx.x & 63, wid = threadIdx.x >> 6;
  if (lane == 0) sred[wid] = v;
  __syncthreads();
  if (threadIdx.x == 0) {
    int nw = ((int)blockDim.x + 63) >> 6;
    float s = 0.f;
    for (int w = 0; w < nw; ++w) s += sred[w];
    atomicAdd(target, s * scale);
  }
}

// ---- kernel 1: argmax assignment + counts ----
__global__ void k_assign(const float* __restrict__ logits, int* __restrict__ cw,
                         int* __restrict__ kb) {
  int b = blockIdx.x * 256 + threadIdx.x;
  if (b >= B_N) return;
  const float* lg = logits + (size_t)b * K_N;
  float best = lg[0]; int bi = 0;
  #pragma unroll
  for (int k = 1; k < K_N; ++k) { float v = lg[k]; if (v > best) { best = v; bi = k; } }
  kb[b] = bi;
  atomicAdd(&cw[bi], 1);
}

// ---- kernel 2: exclusive scan over K=10 ----
__global__ void k_scan(const int* __restrict__ cw, int* __restrict__ offs) {
  if (threadIdx.x == 0) { int s = 0; for (int k = 0; k < K_N; ++k) { offs[k] = s; s += cw[k]; } }
}

// ---- kernel 3: compact scatter of diff vectors per cluster ----
__global__ void k_scatter(const float* __restrict__ emb, const float* __restrict__ cen,
                          const int* __restrict__ kb, const int* __restrict__ offs,
                          int* __restrict__ cursor, float* __restrict__ diffc) {
  int b = blockIdx.x * 256 + threadIdx.x;
  if (b >= B_N) return;
  int k = kb[b];
  int pos = offs[k] + atomicAdd(&cursor[k], 1);
  const float* e = emb + (size_t)b * DIM;
  const float* c = cen + (size_t)k * DIM;
  float* o = diffc + (size_t)pos * DIM;
  #pragma unroll
  for (int d = 0; d < DIM; ++d) o[d] = e[d] - c[d];
}

// ---- kernel 4: p1, p2, p3 (one thread per sorted pair (i<=j)) ----
__global__ __launch_bounds__(576) void k_low(const float* __restrict__ diffc,
                                             const int* __restrict__ cw,
                                             const int* __restrict__ offs,
                                             float* __restrict__ lossAcc) {
  const int k = blockIdx.x;
  const int nb = cw[k], boff = offs[k];
  const int t = threadIdx.x;
  const bool valid = (t < NP);
  int i = 0, j = 0;
  if (valid) {
    while ((j + 1) * (j + 2) / 2 <= t) ++j;
    i = t - j * (j + 1) / 2;
  }
  __shared__ float sd[8][DIM];
  float acc1 = 0.f, acc2 = 0.f, acc3[DIM];
  #pragma unroll
  for (int l = 0; l < DIM; ++l) acc3[l] = 0.f;

  for (int c0 = 0; c0 < nb; c0 += 8) {
    if (t < 256) {
      int bb = t >> 5, d = t & 31;
      int gb = c0 + bb;
      sd[bb][d] = (gb < nb) ? diffc[(size_t)(boff + gb) * DIM + d] : 0.f;
    }
    __syncthreads();
    #pragma unroll
    for (int bb = 0; bb < 8; ++bb) {
      float di = sd[bb][i], dj = sd[bb][j];
      float v = di * dj;
      acc1 += di;
      acc2 += v;
      #pragma unroll
      for (int l = 0; l < DIM; ++l) acc3[l] += v * sd[bb][l];
    }
    __syncthreads();
  }

  float cnt = (float)nb + 1e-7f;
  float cwn = (float)nb * (1.f / (float)B_N);
  float contrib = 0.f;
  if (valid) {
    if (i == j) {            // p1: diagonal thread carries m1 for dim i
      float m1 = acc1 / cnt;
      contrib += cwn * m1 * m1;
    } else {                 // p2: weight 1 per unordered off-diag pair, t2c=0
      float m2 = acc2 / cnt;
      float c2 = c2f(m2);
      contrib += 0.5f * cwn * c2 * c2;
    }
    // p3: unique sorted triples (i<=j<=l), weight w3*N=1, t3c=0, m3 NOT divided
    float s3 = 0.f;
    #pragma unroll
    for (int l = 0; l < DIM; ++l) {
      if (l >= j) { float c3 = c3f(acc3[l]); s3 += c3 * c3; }
    }
    contrib += 0.25f * cwn * s3;
  }
  block_atomic_reduce(contrib, lossAcc, 1.f);
}

// ---- kernel 5: p4 via Gram matrix over sorted pairs (fused compress+loss) ----
__global__ __launch_bounds__(256) void k_m4(const float* __restrict__ diffc,
                                            const int* __restrict__ cw,
                                            const int* __restrict__ offs,
                                            float* __restrict__ lossAcc) {
  const int k = blockIdx.z;
  const int Pt = blockIdx.y, Qt = blockIdx.x;
  const int nb = cw[k], boff = offs[k];
  const int t = threadIdx.x;

  __shared__ __align__(16) float sd[8][DIM];
  __shared__ __align__(16) float svP[8][64];
  __shared__ __align__(16) float svQ[8][64];
  __shared__ unsigned char tIdx[4][64];   // [0]=Pi [1]=Pj [2]=Qi [3]=Qj

  if (t < 128) {
    int which = t >> 6;     // 0 -> P side, 1 -> Q side
    int c = t & 63;
    int Pv = (which ? Qt : Pt) * 64 + c;
    int i = 0, j = 0;
    if (Pv < NP) {
      while ((j + 1) * (j + 2) / 2 <= Pv) ++j;
      i = Pv - j * (j + 1) / 2;
    }
    tIdx[which * 2 + 0][c] = (unsigned char)i;
    tIdx[which * 2 + 1][c] = (unsigned char)j;
  }
  __syncthreads();

  float acc[4][4];
  #pragma unroll
  for (int a = 0; a < 4; ++a)
    #pragma unroll
    for (int c = 0; c < 4; ++c) acc[a][c] = 0.f;

  const int tp = t >> 4, tq = t & 15;

  for (int c0 = 0; c0 < nb; c0 += 8) {
    {
      int bb = t >> 5, d = t & 31;
      int gb = c0 + bb;
      sd[bb][d] = (gb < nb) ? diffc[(size_t)(boff + gb) * DIM + d] : 0.f;
    }
    __syncthreads();
    #pragma unroll
    for (int r = 0; r < 4; ++r) {   // 256 threads compute 8*128 v-values
      int idx = t + r * 256;
      int bb = idx >> 7;
      int c = idx & 127;
      if (c < 64) svP[bb][c]      = sd[bb][tIdx[0][c]]    * sd[bb][tIdx[1][c]];
      else        svQ[bb][c - 64] = sd[bb][tIdx[2][c-64]] * sd[bb][tIdx[3][c-64]];
    }
    __syncthreads();
    #pragma unroll
    for (int bb = 0; bb < 8; ++bb) {
      float4 vp = *reinterpret_cast<const float4*>(&svP[bb][tp * 4]);
      float4 vq = *reinterpret_cast<const float4*>(&svQ[bb][tq * 4]);
      const float vpa[4] = {vp.x, vp.y, vp.z, vp.w};
      const float vqa[4] = {vq.x, vq.y, vq.z, vq.w};
      #pragma unroll
      for (int a = 0; a < 4; ++a)
        #pragma unroll
        for (int c = 0; c < 4; ++c)
          acc[a][c] += vpa[a] * vqa[c];
    }
    __syncthreads();
  }

  // fused epilogue: classify multiset pattern, weight, compress, squared error
  float cwn = (float)nb * (1.f / (float)B_N);
  float sum = 0.f;
  #pragma unroll
  for (int a = 0; a < 4; ++a) {
    int P = Pt * 64 + tp * 4 + a;
    int i = tIdx[0][tp * 4 + a], j = tIdx[1][tp * 4 + a];
    #pragma unroll
    for (int c = 0; c < 4; ++c) {
      int Q = Qt * 64 + tq * 4 + c;
      if (P < NP && Q < NP) {
        int l = tIdx[2][tq * 4 + c], m = tIdx[3][tq * 4 + c];
        // merge the two sorted pairs -> s0<=s1<=s2<=s3
        int s0 = min(i, l), a1 = max(i, l), a2 = min(j, m), s3 = max(j, m);
        int s1 = min(a1, a2), s2 = max(a1, a2);
        bool e01 = (s0 == s1), e12 = (s1 == s2), e23 = (s2 == s3);
        float wgt, tgt = 0.f;
        if (e01 && e12 && e23)              wgt = 0.f;          // (4): off_diag kills all
        else if (e01 && e23)                { wgt = 2.f / 9.f; tgt = T4C1; }  // (2,2)
        else if ((e01 && e12) || (e12 && e23)) wgt = 0.25f;     // (3,1)
        else if (e01 || e12 || e23)         wgt = 5.f / 24.f;   // (2,1,1)
        else                                wgt = 1.f / 6.f;    // (1,1,1,1)
        float d4 = c4f(acc[a][c]) - tgt;
        sum += wgt * d4 * d4;
      }
    }
  }
  block_atomic_reduce(sum, lossAcc, 0.125f * cwn);
}

__global__ void k_final(const float* __restrict__ lossAcc, float* __restrict__ out) {
  if (threadIdx.x == 0 && blockIdx.x == 0) out[0] = lossAcc[0];
}

extern "C" void kernel_launch(void* const* d_in, const int* in_sizes, int n_in,
                              void* d_out, int out_size, void* d_ws, size_t ws_size,
                              hipStream_t stream) {
  const float* emb = (const float*)d_in[0];
  const float* cen = (const float*)d_in[1];
  const float* lg  = (const float*)d_in[2];
  float* out = (float*)d_out;

  int*   wsi    = (int*)d_ws;
  float* wsf    = (float*)d_ws;
  int*   cw     = wsi + WS_CW;
  int*   cursor = wsi + WS_CURSOR;
  int*   offs   = wsi + WS_OFFS;
  float* lossA  = wsf + WS_LOSS;
  int*   kb     = wsi + WS_KB;
  float* diffc  = wsf + WS_DIFFC;

  hipMemsetAsync(d_ws, 0, 64 * 4, stream);                       // cw, cursor, offs, lossAcc
  k_assign <<<B_N / 256, 256, 0, stream>>>(lg, cw, kb);
  k_scan   <<<1, 64, 0, stream>>>(cw, offs);
  k_scatter<<<B_N / 256, 256, 0, stream>>>(emb, cen, kb, offs, cursor, diffc);
  k_low    <<<K_N, 576, 0, stream>>>(diffc, cw, offs, lossA);
  k_m4     <<<dim3(9, 9, K_N), 256, 0, stream>>>(diffc, cw, offs, lossA);
  k_final  <<<1, 64, 0, stream>>>(lossA, out);
}

// Round 2
// 92.078 us; speedup vs baseline: 1.4182x; 1.4182x over previous
//
#include <hip/hip_runtime.h>
#include <math.h>

#define B_N 2048
#define DIM 32
#define K_N 10
#define NP  528          // sorted pairs (i<=j)
#define NCOL 561         // 528 pairs + 32 linear + 1 ones
#define CH 16            // samples per chunk
#define TILE 128
#define NT 5             // tiles per side (5*128 = 640 >= 561)
#define NBLK (NT*NT*K_N)

// ---- ws layout (4-byte words) ----
#define WS_LOSS  0
#define WS_CTR   1
#define WS_CW    2
#define WS_OFFS  12
#define WS_DIFFC 32      // 128B aligned for float4

__device__ __forceinline__ float c2f(float x) {
  float r = sqrtf(fabsf(x) + 0.25f) - 0.5f;
  return (x >= 0.f) ? r : -r;
}
__device__ __forceinline__ float c3f(float x) {
  float r = cbrtf(fabsf(x) + 0.19245008973f) - 0.57735026919f;
  return (x >= 0.f) ? r : -r;
}
__device__ __forceinline__ float c4f(float x) {
  float r = sqrtf(sqrtf(fabsf(x) + 0.15749013123f)) - 0.62996052494f;
  return (x >= 0.f) ? r : -r;
}
#define T4C1 (sqrtf(sqrtf(1.f + 0.15749013123f)) - 0.62996052494f)

__device__ __forceinline__ void decode_col(int g, int& u, int& v) {
  if (g < NP) {
    int j = 0;
    while ((j + 1) * (j + 2) / 2 <= g) ++j;
    u = g - j * (j + 1) / 2; v = j;
  } else if (g < 560) { u = g - NP; v = 32; }
  else if (g == 560)  { u = 32; v = 32; }
  else                { u = 33; v = 33; }   // padded column -> 0
}

// ---- kernel 1: fused assign + scan + scatter + init (single block) ----
__global__ __launch_bounds__(1024) void k_prep(const float* __restrict__ emb,
                                               const float* __restrict__ cen,
                                               const float* __restrict__ lg,
                                               int* __restrict__ cw_g,
                                               int* __restrict__ offs_g,
                                               float* __restrict__ diffc,
                                               float* __restrict__ lossAcc,
                                               int* __restrict__ ctr) {
  __shared__ int scw[K_N], scur[K_N], soffs[K_N];
  __shared__ short skb[B_N];
  const int t = threadIdx.x;
  if (t < K_N) { scw[t] = 0; scur[t] = 0; }
  __syncthreads();
  for (int b = t; b < B_N; b += 1024) {
    const float* l = lg + (size_t)b * K_N;
    float best = l[0]; int bi = 0;
    #pragma unroll
    for (int k = 1; k < K_N; ++k) { float v = l[k]; if (v > best) { best = v; bi = k; } }
    skb[b] = (short)bi;
    atomicAdd(&scw[bi], 1);
  }
  __syncthreads();
  if (t == 0) {
    int s = 0;
    for (int k = 0; k < K_N; ++k) { soffs[k] = s; s += scw[k]; }
    *lossAcc = 0.f; *ctr = 0;
  }
  __syncthreads();
  if (t < K_N) { cw_g[t] = scw[t]; offs_g[t] = soffs[t]; }
  for (int b = t; b < B_N; b += 1024) {
    int k = skb[b];
    int pos = soffs[k] + atomicAdd(&scur[k], 1);
    const float4* e4 = reinterpret_cast<const float4*>(emb + (size_t)b * DIM);
    const float4* c4p = reinterpret_cast<const float4*>(cen + (size_t)k * DIM);
    float4* o4 = reinterpret_cast<float4*>(diffc + (size_t)pos * DIM);
    #pragma unroll
    for (int q = 0; q < 8; ++q) {
      float4 e = e4[q], c = c4p[q];
      o4[q] = make_float4(e.x - c.x, e.y - c.y, e.z - c.z, e.w - c.w);
    }
  }
}

// ---- kernel 2: augmented Gram + fused loss (p1..p4) ----
__global__ __launch_bounds__(256) void k_main(const float* __restrict__ diffc,
                                              const int* __restrict__ cw,
                                              const int* __restrict__ offs,
                                              float* __restrict__ lossAcc,
                                              int* __restrict__ ctr,
                                              float* __restrict__ out) {
  const int k  = blockIdx.z;
  const int Pt = blockIdx.y, Qt = blockIdx.x;
  const int nb = cw[k], boff = offs[k];
  const int t  = threadIdx.x;

  __shared__ __align__(16) float sd[CH][40];      // [32]=ones, [33]=zero
  __shared__ __align__(16) float svP[CH][TILE];
  __shared__ __align__(16) float svQ[CH][TILE];
  __shared__ unsigned char tIP[2][TILE];
  __shared__ unsigned char tIQ[2][TILE];
  __shared__ float sred[8];

  // decode my column (each thread owns one column of one side)
  int myu, myv;
  {
    int side = t >> 7;          // 0 = P side, 1 = Q side
    int c = t & 127;
    int g = (side ? Qt : Pt) * TILE + c;
    decode_col(g, myu, myv);
    if (side) { tIQ[0][c] = (unsigned char)myu; tIQ[1][c] = (unsigned char)myv; }
    else      { tIP[0][c] = (unsigned char)myu; tIP[1][c] = (unsigned char)myv; }
  }
  __syncthreads();

  float acc[8][8];
  #pragma unroll
  for (int a = 0; a < 8; ++a)
    #pragma unroll
    for (int c = 0; c < 8; ++c) acc[a][c] = 0.f;

  const int tp = t >> 4, tq = t & 15;

  for (int c0 = 0; c0 < nb; c0 += CH) {
    if (t < 128) {
      int bb = t >> 3, d4 = t & 7;
      int gb = c0 + bb;
      float4 v = make_float4(0.f, 0.f, 0.f, 0.f);
      if (gb < nb) v = *reinterpret_cast<const float4*>(&diffc[(size_t)(boff + gb) * DIM + d4 * 4]);
      *reinterpret_cast<float4*>(&sd[bb][d4 * 4]) = v;
    } else if (t < 144) {
      int bb = t - 128;
      sd[bb][32] = (c0 + bb < nb) ? 1.f : 0.f;
      sd[bb][33] = 0.f;
    }
    __syncthreads();
    {   // column products: thread t fills its column for all CH samples
      int c = t & 127;
      float* dst = (t < 128) ? &svP[0][c] : &svQ[0][c];
      #pragma unroll
      for (int bb = 0; bb < CH; ++bb)
        dst[bb * TILE] = sd[bb][myu] * sd[bb][myv];
    }
    __syncthreads();
    #pragma unroll
    for (int bb = 0; bb < CH; ++bb) {
      float4 p0 = *reinterpret_cast<const float4*>(&svP[bb][tp * 8]);
      float4 p1 = *reinterpret_cast<const float4*>(&svP[bb][tp * 8 + 4]);
      float4 q0 = *reinterpret_cast<const float4*>(&svQ[bb][tq * 8]);
      float4 q1 = *reinterpret_cast<const float4*>(&svQ[bb][tq * 8 + 4]);
      float pa[8] = {p0.x, p0.y, p0.z, p0.w, p1.x, p1.y, p1.z, p1.w};
      float qa[8] = {q0.x, q0.y, q0.z, q0.w, q1.x, q1.y, q1.z, q1.w};
      #pragma unroll
      for (int a = 0; a < 8; ++a)
        #pragma unroll
        for (int c = 0; c < 8; ++c)
          acc[a][c] += pa[a] * qa[c];
    }
    __syncthreads();
  }

  // ---- fused epilogue ----
  const float inv_cnt = 1.f / ((float)nb + 1e-7f);
  float sum = 0.f;
  #pragma unroll
  for (int a = 0; a < 8; ++a) {
    int P = Pt * TILE + tp * 8 + a;
    int i = tIP[0][tp * 8 + a], j = tIP[1][tp * 8 + a];
    #pragma unroll
    for (int c = 0; c < 8; ++c) {
      int Q = Qt * TILE + tq * 8 + c;
      int l = tIQ[0][tq * 8 + c], m = tIQ[1][tq * 8 + c];
      float g = acc[a][c];
      if (P < NP) {
        if (Q < NP) {
          // p4: merge sorted pairs -> s0<=s1<=s2<=s3, classify multiset
          int s0 = min(i, l), a1 = max(i, l), a2 = min(j, m), s3 = max(j, m);
          int s1 = min(a1, a2), s2 = max(a1, a2);
          bool e01 = (s0 == s1), e12 = (s1 == s2), e23 = (s2 == s3);
          float wgt, tgt = 0.f;
          if (e01 && e12 && e23)                 wgt = 0.f;
          else if (e01 && e23)                   { wgt = 2.f / 9.f; tgt = T4C1; }
          else if ((e01 && e12) || (e12 && e23)) wgt = 0.25f;
          else if (e01 || e12 || e23)            wgt = 5.f / 24.f;
          else                                   wgt = 1.f / 6.f;
          float d = c4f(g) - tgt;
          sum += 0.125f * wgt * d * d;
        } else if (Q < 560) {
          int ll = Q - NP;                        // p3: unique triple i<=j<=ll
          if (ll >= j) { float d = c3f(g); sum += 0.25f * d * d; }
        } else if (Q == 560) {                    // p2 (off-diag pairs only)
          if (i < j) { float d = c2f(g * inv_cnt); sum += 0.5f * d * d; }
        }
      } else if (P < 560 && Q == 560) {           // p1
        float m1 = g * inv_cnt;
        sum += m1 * m1;
      }
    }
  }

  // block reduce + device accumulate
  #pragma unroll
  for (int off = 32; off > 0; off >>= 1) sum += __shfl_down(sum, off, 64);
  int lane = t & 63, wid = t >> 6;
  if (lane == 0) sred[wid] = sum;
  __syncthreads();
  if (t == 0) {
    float s = sred[0] + sred[1] + sred[2] + sred[3];
    atomicAdd(lossAcc, s * ((float)nb / (float)B_N));
    __threadfence();
    int done = atomicAdd(ctr, 1);
    if (done == NBLK - 1) out[0] = atomicAdd(lossAcc, 0.f);
  }
}

extern "C" void kernel_launch(void* const* d_in, const int* in_sizes, int n_in,
                              void* d_out, int out_size, void* d_ws, size_t ws_size,
                              hipStream_t stream) {
  const float* emb = (const float*)d_in[0];
  const float* cen = (const float*)d_in[1];
  const float* lg  = (const float*)d_in[2];
  float* out = (float*)d_out;

  int*   wsi   = (int*)d_ws;
  float* wsf   = (float*)d_ws;
  float* lossA = wsf + WS_LOSS;
  int*   ctr   = wsi + WS_CTR;
  int*   cw    = wsi + WS_CW;
  int*   offsp = wsi + WS_OFFS;
  float* diffc = wsf + WS_DIFFC;

  k_prep<<<1, 1024, 0, stream>>>(emb, cen, lg, cw, offsp, diffc, lossA, ctr);
  k_main<<<dim3(NT, NT, K_N), 256, 0, stream>>>(diffc, cw, offsp, lossA, ctr, out);
}